// Round 1
// baseline (2861.837 us; speedup 1.0000x reference)
//
#include <hip/hip_runtime.h>

#define H      64
#define NSLOT  4
#define NSTEP  23          // SEQ_LEN - 1
#define NB     65536
#define NV     66          // VOCAB_SIZE + 2
#define SEQL   24

// ---- workspace layout (float offsets) ----
#define OFF_EW1   0                         // embW1b  [NV][H]   = embed@W1[:64] + b1
#define OFF_EWR1  (NV * H)                  // embWr1b [NV][H]   = embed@Wr1[:64] + br1
#define OFF_SEQT  (2 * NV * H)              // seqT    [NSTEP][NB]  (int32)
#define OFF_MEM   (2 * NV * H + NSTEP * NB) // mem     [NB][NSLOT][H]
// total = 8448 + 1507328 + 16777216 floats  ~= 73.2 MB

__global__ __launch_bounds__(256) void k_setup_tables(
    const float* __restrict__ embed, const float* __restrict__ W1, const float* __restrict__ b1,
    const float* __restrict__ Wr1, const float* __restrict__ br1, float* __restrict__ ws)
{
    int idx = blockIdx.x * 256 + threadIdx.x;
    if (idx >= NV * H) return;
    int t = idx >> 6, k = idx & 63;
    float a1 = b1[k], a2 = br1[k];
    for (int j = 0; j < H; ++j) {
        float e = embed[t * H + j];
        a1 = fmaf(e, W1[j * H + k], a1);
        a2 = fmaf(e, Wr1[j * H + k], a2);
    }
    ws[OFF_EW1 + idx]  = a1;
    ws[OFF_EWR1 + idx] = a2;
}

__global__ __launch_bounds__(256) void k_setup_seqT(
    const int* __restrict__ seqs, float* __restrict__ ws)
{
    int b = blockIdx.x * 256 + threadIdx.x;
    int* seqT = (int*)ws + OFF_SEQT;
#pragma unroll
    for (int t = 0; t < NSTEP; ++t) seqT[t * NB + b] = seqs[b * SEQL + t];
}

__global__ __launch_bounds__(256, 2) void k_main(
    const float* __restrict__ W1, const float* __restrict__ W2, const float* __restrict__ b2,
    const float* __restrict__ Ww, const float* __restrict__ bw,
    const float* __restrict__ We, const float* __restrict__ be,
    const float* __restrict__ Wr1, const float* __restrict__ Wr2, const float* __restrict__ br2,
    const int* __restrict__ qtok, float* __restrict__ ws, float* __restrict__ out)
{
    // per-lane private LDS column for dynamic-index activation broadcast:
    // lds[j*256 + tid], bank = tid%32 -> 2 lanes/bank (free on CDNA4)
    __shared__ float lds[H * 256];
    const int tid = threadIdx.x;
    const int b   = blockIdx.x * 256 + tid;

    const float* embW1b  = ws + OFF_EW1;
    const float* embWr1b = ws + OFF_EWR1;
    const int*   seqT    = (const int*)ws + OFF_SEQT;
    float*       memp    = ws + OFF_MEM + (size_t)b * (NSLOT * H);

    // zero-init this lane's memory state (ws is poisoned each launch)
    float4 z4 = make_float4(0.f, 0.f, 0.f, 0.f);
#pragma unroll
    for (int i = 0; i < NSLOT * H / 4; ++i) ((float4*)memp)[i] = z4;

    float contrib[H];   // running  sum_s mem[s] @ W1mem_s
#pragma unroll
    for (int k = 0; k < H; ++k) contrib[k] = 0.f;

    float acc[H];

    for (int t = 0; t < NSTEP; ++t) {
        int tok = seqT[t * NB + b];
        const float4* row = (const float4*)(embW1b + tok * H);

        // h1 = relu(embW1b[tok] + contrib)  -> lds
#pragma unroll
        for (int kq = 0; kq < H / 4; ++kq) {
            float4 r = row[kq];
            lds[(kq * 4 + 0) * 256 + tid] = fmaxf(r.x + contrib[kq * 4 + 0], 0.f);
            lds[(kq * 4 + 1) * 256 + tid] = fmaxf(r.y + contrib[kq * 4 + 1], 0.f);
            lds[(kq * 4 + 2) * 256 + tid] = fmaxf(r.z + contrib[kq * 4 + 2], 0.f);
            lds[(kq * 4 + 3) * 256 + tid] = fmaxf(r.w + contrib[kq * 4 + 3], 0.f);
        }

        // h2 = relu(h1 @ W2 + b2)   (W2 reads are wave-uniform -> s_load)
#pragma unroll
        for (int k = 0; k < H; ++k) acc[k] = b2[k];
#pragma unroll 2
        for (int j = 0; j < H; ++j) {
            float a = lds[j * 256 + tid];
#pragma unroll
            for (int k = 0; k < H; ++k) acc[k] = fmaf(a, W2[j * H + k], acc[k]);
        }
#pragma unroll
        for (int k = 0; k < H; ++k) lds[k * 256 + tid] = fmaxf(acc[k], 0.f);

        // write_vec = h2 @ Ww + bw ; evict_logits = h2 @ We + be  (fused over j)
        float l0 = be[0], l1 = be[1], l2 = be[2], l3 = be[3];
#pragma unroll
        for (int k = 0; k < H; ++k) acc[k] = bw[k];
#pragma unroll 2
        for (int j = 0; j < H; ++j) {
            float a = lds[j * 256 + tid];
#pragma unroll
            for (int k = 0; k < H; ++k) acc[k] = fmaf(a, Ww[j * H + k], acc[k]);
            l0 = fmaf(a, We[j * NSLOT + 0], l0);
            l1 = fmaf(a, We[j * NSLOT + 1], l1);
            l2 = fmaf(a, We[j * NSLOT + 2], l2);
            l3 = fmaf(a, We[j * NSLOT + 3], l3);
        }

        // argmax, first-max wins (matches jnp.argmax)
        int e = 0; float best = l0;
        if (l1 > best) { best = l1; e = 1; }
        if (l2 > best) { best = l2; e = 2; }
        if (l3 > best) { best = l3; e = 3; }

        // delta = write_vec - mem_old[e]; mem[e] = write_vec; delta -> lds
        float* slot = memp + e * H;
#pragma unroll
        for (int kq = 0; kq < H / 4; ++kq) {
            float4 old = ((const float4*)slot)[kq];
            float4 w4  = make_float4(acc[kq * 4 + 0], acc[kq * 4 + 1],
                                     acc[kq * 4 + 2], acc[kq * 4 + 3]);
            ((float4*)slot)[kq] = w4;
            lds[(kq * 4 + 0) * 256 + tid] = w4.x - old.x;
            lds[(kq * 4 + 1) * 256 + tid] = w4.y - old.y;
            lds[(kq * 4 + 2) * 256 + tid] = w4.z - old.z;
            lds[(kq * 4 + 3) * 256 + tid] = w4.w - old.w;
        }

        // contrib += delta @ W1mem_e   (per-lane slot-selected weights, L1/L2 multicast)
        const float4* Wm = (const float4*)(W1 + (H + e * H) * H);
#pragma unroll 2
        for (int m = 0; m < H; ++m) {
            float d = lds[m * 256 + tid];
#pragma unroll
            for (int kq = 0; kq < H / 4; ++kq) {
                float4 w = Wm[m * 16 + kq];
                contrib[kq * 4 + 0] = fmaf(d, w.x, contrib[kq * 4 + 0]);
                contrib[kq * 4 + 1] = fmaf(d, w.y, contrib[kq * 4 + 1]);
                contrib[kq * 4 + 2] = fmaf(d, w.z, contrib[kq * 4 + 2]);
                contrib[kq * 4 + 3] = fmaf(d, w.w, contrib[kq * 4 + 3]);
            }
        }
    }

    // ---- read head ----
    // msum = mean over slots -> lds
#pragma unroll
    for (int k = 0; k < H; ++k) acc[k] = 0.f;
#pragma unroll
    for (int s = 0; s < NSLOT; ++s) {
#pragma unroll
        for (int kq = 0; kq < H / 4; ++kq) {
            float4 v = ((const float4*)(memp + s * H))[kq];
            acc[kq * 4 + 0] += v.x;
            acc[kq * 4 + 1] += v.y;
            acc[kq * 4 + 2] += v.z;
            acc[kq * 4 + 3] += v.w;
        }
    }
#pragma unroll
    for (int k = 0; k < H; ++k) lds[k * 256 + tid] = acc[k] * 0.25f;

    // r2 = relu(embWr1b[q] + msum @ Wr1[64:128])
    int q = qtok[b];
    const float4* qrow = (const float4*)(embWr1b + q * H);
#pragma unroll
    for (int kq = 0; kq < H / 4; ++kq) {
        float4 r = qrow[kq];
        acc[kq * 4 + 0] = r.x; acc[kq * 4 + 1] = r.y;
        acc[kq * 4 + 2] = r.z; acc[kq * 4 + 3] = r.w;
    }
#pragma unroll 2
    for (int j = 0; j < H; ++j) {
        float a = lds[j * 256 + tid];
#pragma unroll
        for (int k = 0; k < H; ++k) acc[k] = fmaf(a, Wr1[(H + j) * H + k], acc[k]);
    }
#pragma unroll
    for (int k = 0; k < H; ++k) lds[k * 256 + tid] = fmaxf(acc[k], 0.f);

    // logits = r2 @ Wr2 + br2
#pragma unroll
    for (int k = 0; k < H; ++k) acc[k] = br2[k];
#pragma unroll 2
    for (int j = 0; j < H; ++j) {
        float a = lds[j * 256 + tid];
#pragma unroll
        for (int k = 0; k < H; ++k) acc[k] = fmaf(a, Wr2[j * H + k], acc[k]);
    }

    float4* outp = (float4*)(out + (size_t)b * H);
#pragma unroll
    for (int kq = 0; kq < H / 4; ++kq)
        outp[kq] = make_float4(acc[kq * 4 + 0], acc[kq * 4 + 1],
                               acc[kq * 4 + 2], acc[kq * 4 + 3]);
}

extern "C" void kernel_launch(void* const* d_in, const int* in_sizes, int n_in,
                              void* d_out, int out_size, void* d_ws, size_t ws_size,
                              hipStream_t stream)
{
    const int*   seqs  = (const int*)d_in[0];
    const int*   qtok  = (const int*)d_in[1];
    const float* embed = (const float*)d_in[2];
    const float* W1    = (const float*)d_in[3];
    const float* b1    = (const float*)d_in[4];
    const float* W2    = (const float*)d_in[5];
    const float* b2    = (const float*)d_in[6];
    const float* Ww    = (const float*)d_in[7];
    const float* bw    = (const float*)d_in[8];
    const float* We    = (const float*)d_in[9];
    const float* be    = (const float*)d_in[10];
    const float* Wr1   = (const float*)d_in[11];
    const float* br1   = (const float*)d_in[12];
    const float* Wr2   = (const float*)d_in[13];
    const float* br2   = (const float*)d_in[14];
    float* out = (float*)d_out;
    float* ws  = (float*)d_ws;

    hipLaunchKernelGGL(k_setup_tables, dim3((NV * H + 255) / 256), dim3(256), 0, stream,
                       embed, W1, b1, Wr1, br1, ws);
    hipLaunchKernelGGL(k_setup_seqT, dim3(NB / 256), dim3(256), 0, stream, seqs, ws);
    hipLaunchKernelGGL(k_main, dim3(NB / 256), dim3(256), 0, stream,
                       W1, W2, b2, Ww, bw, We, be, Wr1, Wr2, br2, qtok, ws, out);
}

// Round 2
// 2210.055 us; speedup vs baseline: 1.2949x; 1.2949x over previous
//
#include <hip/hip_runtime.h>

#define H      64
#define NSLOT  4
#define NSTEP  23          // SEQ_LEN - 1
#define NB     65536
#define NV     66          // VOCAB_SIZE + 2
#define SEQL   24

// ---- workspace layout (float offsets) ----
#define OFF_EW1   0                         // embW1b  [NV][H]   = embed@W1[:64] + b1
#define OFF_EWR1  (NV * H)                  // embWr1b [NV][H]   = embed@Wr1[:64] + br1
#define OFF_SEQT  (2 * NV * H)              // seqT    [NSTEP][NB]  (int32)
#define OFF_MEM   (2 * NV * H + NSTEP * NB) // mem     [NB][NSLOT][H]

__global__ __launch_bounds__(256) void k_setup_tables(
    const float* __restrict__ embed, const float* __restrict__ W1, const float* __restrict__ b1,
    const float* __restrict__ Wr1, const float* __restrict__ br1, float* __restrict__ ws)
{
    int idx = blockIdx.x * 256 + threadIdx.x;
    if (idx >= NV * H) return;
    int t = idx >> 6, k = idx & 63;
    float a1 = b1[k], a2 = br1[k];
    for (int j = 0; j < H; ++j) {
        float e = embed[t * H + j];
        a1 = fmaf(e, W1[j * H + k], a1);
        a2 = fmaf(e, Wr1[j * H + k], a2);
    }
    ws[OFF_EW1 + idx]  = a1;
    ws[OFF_EWR1 + idx] = a2;
}

__global__ __launch_bounds__(256) void k_setup_seqT(
    const int* __restrict__ seqs, float* __restrict__ ws)
{
    int b = blockIdx.x * 256 + threadIdx.x;
    int* seqT = (int*)ws + OFF_SEQT;
#pragma unroll
    for (int t = 0; t < NSTEP; ++t) seqT[t * NB + b] = seqs[b * SEQL + t];
}

__global__ __launch_bounds__(256) void k_main(
    const float* __restrict__ W1, const float* __restrict__ W2, const float* __restrict__ b2,
    const float* __restrict__ Ww, const float* __restrict__ bw,
    const float* __restrict__ We, const float* __restrict__ be,
    const float* __restrict__ Wr1, const float* __restrict__ Wr2, const float* __restrict__ br2,
    const int* __restrict__ qtok, float* __restrict__ ws, float* __restrict__ out)
{
    // per-lane private LDS column: lds[j*256 + tid], bank = tid%32 -> 2-way (free).
    // Lets j-loops stay ROLLED (small I$ body) while activations are dynamically indexed.
    __shared__ float lds[H * 256];
    const int tid = threadIdx.x;
    const int b   = blockIdx.x * 256 + tid;

    const float* embW1b  = ws + OFF_EW1;
    const float* embWr1b = ws + OFF_EWR1;
    const int*   seqT    = (const int*)ws + OFF_SEQT;
    float*       memp    = ws + OFF_MEM + (size_t)b * (NSLOT * H);

    // zero-init this lane's memory state (ws is poisoned each launch)
    float4 z4 = make_float4(0.f, 0.f, 0.f, 0.f);
#pragma unroll
    for (int i = 0; i < NSLOT * H / 4; ++i) ((float4*)memp)[i] = z4;

    float contrib[H];   // running  sum_s mem[s] @ W1mem_s
#pragma unroll
    for (int k = 0; k < H; ++k) contrib[k] = 0.f;

    float acc[H];

#pragma unroll 1
    for (int t = 0; t < NSTEP; ++t) {
        int tok = seqT[t * NB + b];
        const float4* row = (const float4*)(embW1b + tok * H);

        // h1 = relu(embW1b[tok] + contrib)  -> lds
#pragma unroll
        for (int kq = 0; kq < H / 4; ++kq) {
            float4 r = row[kq];
            lds[(kq * 4 + 0) * 256 + tid] = fmaxf(r.x + contrib[kq * 4 + 0], 0.f);
            lds[(kq * 4 + 1) * 256 + tid] = fmaxf(r.y + contrib[kq * 4 + 1], 0.f);
            lds[(kq * 4 + 2) * 256 + tid] = fmaxf(r.z + contrib[kq * 4 + 2], 0.f);
            lds[(kq * 4 + 3) * 256 + tid] = fmaxf(r.w + contrib[kq * 4 + 3], 0.f);
        }

        // h2 = relu(h1 @ W2 + b2)   (W2 wave-uniform -> s_load)
#pragma unroll
        for (int k = 0; k < H; ++k) acc[k] = b2[k];
#pragma unroll 2
        for (int j = 0; j < H; ++j) {
            float a = lds[j * 256 + tid];
#pragma unroll
            for (int k = 0; k < H; ++k) acc[k] = fmaf(a, W2[j * H + k], acc[k]);
        }
#pragma unroll
        for (int k = 0; k < H; ++k) lds[k * 256 + tid] = fmaxf(acc[k], 0.f);

        // write_vec = h2 @ Ww + bw ; evict_logits = h2 @ We + be  (fused over j)
        float l0 = be[0], l1 = be[1], l2 = be[2], l3 = be[3];
#pragma unroll
        for (int k = 0; k < H; ++k) acc[k] = bw[k];
#pragma unroll 2
        for (int j = 0; j < H; ++j) {
            float a = lds[j * 256 + tid];
#pragma unroll
            for (int k = 0; k < H; ++k) acc[k] = fmaf(a, Ww[j * H + k], acc[k]);
            l0 = fmaf(a, We[j * NSLOT + 0], l0);
            l1 = fmaf(a, We[j * NSLOT + 1], l1);
            l2 = fmaf(a, We[j * NSLOT + 2], l2);
            l3 = fmaf(a, We[j * NSLOT + 3], l3);
        }

        // argmax, first-max wins (matches jnp.argmax)
        int e = 0; float best = l0;
        if (l1 > best) { best = l1; e = 1; }
        if (l2 > best) { best = l2; e = 2; }
        if (l3 > best) { best = l3; e = 3; }

        // delta = write_vec - mem_old[e]; mem[e] = write_vec; delta -> lds
        float* slot = memp + e * H;
#pragma unroll
        for (int kq = 0; kq < H / 4; ++kq) {
            float4 old = ((const float4*)slot)[kq];
            float4 w4  = make_float4(acc[kq * 4 + 0], acc[kq * 4 + 1],
                                     acc[kq * 4 + 2], acc[kq * 4 + 3]);
            ((float4*)slot)[kq] = w4;
            lds[(kq * 4 + 0) * 256 + tid] = w4.x - old.x;
            lds[(kq * 4 + 1) * 256 + tid] = w4.y - old.y;
            lds[(kq * 4 + 2) * 256 + tid] = w4.z - old.z;
            lds[(kq * 4 + 3) * 256 + tid] = w4.w - old.w;
        }

        // contrib += delta @ W1mem_e, computed as masked projection through ALL
        // four slot matrices so every weight access is wave-uniform (s_load,
        // scalar cache) instead of a per-lane e-indexed VMEM gather.
        // md = (e==s) ? delta_j : 0   =>  exact: 0*w adds nothing.
#pragma unroll 1
        for (int s = 0; s < NSLOT; ++s) {
            float ms = (e == s) ? 1.0f : 0.0f;
            const float* Ws = W1 + (H + s * H) * H;
#pragma unroll 2
            for (int j = 0; j < H; ++j) {
                float md = ms * lds[j * 256 + tid];
#pragma unroll
                for (int k = 0; k < H; ++k)
                    contrib[k] = fmaf(md, Ws[j * H + k], contrib[k]);
            }
        }
    }

    // ---- read head ----
    // msum = mean over slots -> lds
#pragma unroll
    for (int k = 0; k < H; ++k) acc[k] = 0.f;
#pragma unroll
    for (int s = 0; s < NSLOT; ++s) {
#pragma unroll
        for (int kq = 0; kq < H / 4; ++kq) {
            float4 v = ((const float4*)(memp + s * H))[kq];
            acc[kq * 4 + 0] += v.x;
            acc[kq * 4 + 1] += v.y;
            acc[kq * 4 + 2] += v.z;
            acc[kq * 4 + 3] += v.w;
        }
    }
#pragma unroll
    for (int k = 0; k < H; ++k) lds[k * 256 + tid] = acc[k] * 0.25f;

    // r2 = relu(embWr1b[q] + msum @ Wr1[64:128])
    int q = qtok[b];
    const float4* qrow = (const float4*)(embWr1b + q * H);
#pragma unroll
    for (int kq = 0; kq < H / 4; ++kq) {
        float4 r = qrow[kq];
        acc[kq * 4 + 0] = r.x; acc[kq * 4 + 1] = r.y;
        acc[kq * 4 + 2] = r.z; acc[kq * 4 + 3] = r.w;
    }
#pragma unroll 2
    for (int j = 0; j < H; ++j) {
        float a = lds[j * 256 + tid];
#pragma unroll
        for (int k = 0; k < H; ++k) acc[k] = fmaf(a, Wr1[(H + j) * H + k], acc[k]);
    }
#pragma unroll
    for (int k = 0; k < H; ++k) lds[k * 256 + tid] = fmaxf(acc[k], 0.f);

    // logits = r2 @ Wr2 + br2
#pragma unroll
    for (int k = 0; k < H; ++k) acc[k] = br2[k];
#pragma unroll 2
    for (int j = 0; j < H; ++j) {
        float a = lds[j * 256 + tid];
#pragma unroll
        for (int k = 0; k < H; ++k) acc[k] = fmaf(a, Wr2[j * H + k], acc[k]);
    }

    float4* outp = (float4*)(out + (size_t)b * H);
#pragma unroll
    for (int kq = 0; kq < H / 4; ++kq)
        outp[kq] = make_float4(acc[kq * 4 + 0], acc[kq * 4 + 1],
                               acc[kq * 4 + 2], acc[kq * 4 + 3]);
}

extern "C" void kernel_launch(void* const* d_in, const int* in_sizes, int n_in,
                              void* d_out, int out_size, void* d_ws, size_t ws_size,
                              hipStream_t stream)
{
    const int*   seqs  = (const int*)d_in[0];
    const int*   qtok  = (const int*)d_in[1];
    const float* embed = (const float*)d_in[2];
    const float* W1    = (const float*)d_in[3];
    const float* b1    = (const float*)d_in[4];
    const float* W2    = (const float*)d_in[5];
    const float* b2    = (const float*)d_in[6];
    const float* Ww    = (const float*)d_in[7];
    const float* bw    = (const float*)d_in[8];
    const float* We    = (const float*)d_in[9];
    const float* be    = (const float*)d_in[10];
    const float* Wr1   = (const float*)d_in[11];
    const float* br1   = (const float*)d_in[12];
    const float* Wr2   = (const float*)d_in[13];
    const float* br2   = (const float*)d_in[14];
    float* out = (float*)d_out;
    float* ws  = (float*)d_ws;

    hipLaunchKernelGGL(k_setup_tables, dim3((NV * H + 255) / 256), dim3(256), 0, stream,
                       embed, W1, b1, Wr1, br1, ws);
    hipLaunchKernelGGL(k_setup_seqT, dim3(NB / 256), dim3(256), 0, stream, seqs, ws);
    hipLaunchKernelGGL(k_main, dim3(NB / 256), dim3(256), 0, stream,
                       W1, W2, b2, Ww, bw, We, be, Wr1, Wr2, br2, qtok, ws, out);
}